// Round 8
// baseline (307.692 us; speedup 1.0000x reference)
//
#include <hip/hip_runtime.h>
#include <math.h>

#define T_DIM 2048
#define B_DIM 64
#define H_DIM 1024
#define TC 16  // t-values per block in scores kernel

typedef float f4 __attribute__((ext_vector_type(4)));

// ---------------------------------------------------------------------------
// K1: q[b,h] = sum_g hidden[b,g] * W[g,h]
// grid (4, 16), block 512 = 8 waves. Block: 4 b-rows x 256 h-cols; one W load
// feeds 4 b-accumulators. LDS reduce across waves.
// Also zeroes the 4 group-completion counters used by K2's last-block fusion
// (same-stream ordering makes them visible before K2 starts).
// b_attn is constant in t under softmax -> dropped exactly.
// ---------------------------------------------------------------------------
__global__ __launch_bounds__(512) void qproj_kernel(
    const float* __restrict__ hidden,
    const float* __restrict__ W,
    float* __restrict__ q,
    int* __restrict__ counters) {
    if (blockIdx.x == 0 && blockIdx.y == 0 && threadIdx.x < 4)
        counters[threadIdx.x] = 0;

    const int b0   = blockIdx.y * 4;
    const int h0   = blockIdx.x * 256;
    const int wave = threadIdx.x >> 6;
    const int lane = threadIdx.x & 63;

    __shared__ float hs[4][H_DIM];
    __shared__ f4    part[8][4][64];

    for (int i = threadIdx.x; i < 4 * H_DIM; i += 512)
        hs[i >> 10][i & 1023] = hidden[(size_t)b0 * H_DIM + i];
    __syncthreads();

    const int gbase = wave * 128;
    const f4* Wv = (const f4*)(W + (size_t)gbase * H_DIM + h0);
    f4 acc0 = {0,0,0,0}, acc1 = {0,0,0,0}, acc2 = {0,0,0,0}, acc3 = {0,0,0,0};
#pragma unroll 4
    for (int g = 0; g < 128; ++g) {
        const f4 wv = Wv[g * 256 + lane];
        acc0 += hs[0][gbase + g] * wv;
        acc1 += hs[1][gbase + g] * wv;
        acc2 += hs[2][gbase + g] * wv;
        acc3 += hs[3][gbase + g] * wv;
    }
    part[wave][0][lane] = acc0;
    part[wave][1][lane] = acc1;
    part[wave][2][lane] = acc2;
    part[wave][3][lane] = acc3;
    __syncthreads();

    if (wave < 4) {  // wave w reduces b-row w
        f4 s = part[0][wave][lane];
#pragma unroll
        for (int w = 1; w < 8; ++w) s += part[w][wave][lane];
        ((f4*)(q + (size_t)(b0 + wave) * H_DIM + h0))[lane] = s;
    }
}

// ---------------------------------------------------------------------------
// K2 (dominant) + fused softmax tail:
//   scores[b][t] = sum_h enc[t,b,h] * q[b,h]
// 2 rows (b, b+1) per wave; qf in registers; nt enc loads; parity butterfly.
// grid (T/TC, B/16) = (128, 4) = 512 blocks, 512 thr (8 waves).
// Completion: device-scope atomicAdd per b-group y; the LAST (128th) block of
// each group runs the row softmax for its 16 b-rows (scores L2-hot).
// No spin-waits -> deadlock-free under any dispatch order.
// ---------------------------------------------------------------------------
__global__ __launch_bounds__(512) void scores_softmax_kernel(
    const float* __restrict__ enc,
    const float* __restrict__ q,
    float* __restrict__ scores,
    int* __restrict__ counters,
    float* __restrict__ out) {
    const int wave = threadIdx.x >> 6;
    const int lane = threadIdx.x & 63;
    const int y    = blockIdx.y;
    const int t0   = blockIdx.x * TC;
    const int b0   = y * 16 + wave * 2;

    f4 qf0[4], qf1[4];
    {
        const f4* qv0 = (const f4*)(q + (size_t)b0 * H_DIM);
        const f4* qv1 = (const f4*)(q + (size_t)(b0 + 1) * H_DIM);
#pragma unroll
        for (int k = 0; k < 4; ++k) {
            qf0[k] = qv0[k * 64 + lane];
            qf1[k] = qv1[k * 64 + lane];
        }
    }

#pragma unroll 2
    for (int tt = 0; tt < TC; ++tt) {
        const int t = t0 + tt;
        const f4* e0p = (const f4*)(enc + ((size_t)t * B_DIM + b0) * H_DIM);
        const f4* e1p = e0p + 256;  // row b0+1

        f4 E0[4], E1[4];
#pragma unroll
        for (int k = 0; k < 4; ++k)
            E0[k] = __builtin_nontemporal_load(&e0p[k * 64 + lane]);
#pragma unroll
        for (int k = 0; k < 4; ++k)
            E1[k] = __builtin_nontemporal_load(&e1p[k * 64 + lane]);

        float a0 = 0.f, a1 = 0.f;
#pragma unroll
        for (int k = 0; k < 4; ++k) {
            a0 += E0[k].x * qf0[k].x + E0[k].y * qf0[k].y +
                  E0[k].z * qf0[k].z + E0[k].w * qf0[k].w;
            a1 += E1[k].x * qf1[k].x + E1[k].y * qf1[k].y +
                  E1[k].z * qf1[k].z + E1[k].w * qf1[k].w;
        }

        // Parity butterfly: lane parity selects which row's sum it carries.
        const bool odd = lane & 1;
        float m = odd ? a1 : a0;
        float o = odd ? a0 : a1;
        m += __shfl_xor(o, 1);
#pragma unroll
        for (int off = 2; off < 64; off <<= 1)
            m += __shfl_xor(m, off);

        if (lane < 2)
            scores[(size_t)(b0 + lane) * T_DIM + t] = m;
    }

    // ---- completion protocol (release: fence THEN atomic) ----
    __threadfence();
    __shared__ int done;
    if (threadIdx.x == 0) done = atomicAdd(&counters[y], 1);
    __syncthreads();
    if (done != gridDim.x - 1) return;
    __threadfence();  // acquire side

    // ---- last block of group y: softmax for rows y*16 .. y*16+15 ----
    __shared__ float redm[8], reds[8];
    const int tid = threadIdx.x;
    for (int r = 0; r < 16; ++r) {
        const int b = y * 16 + r;
        f4 v = ((const f4*)(scores + (size_t)b * T_DIM))[tid];

        float m = fmaxf(fmaxf(v.x, v.y), fmaxf(v.z, v.w));
#pragma unroll
        for (int off = 1; off < 64; off <<= 1)
            m = fmaxf(m, __shfl_xor(m, off));
        if (lane == 0) redm[wave] = m;
        __syncthreads();
        m = redm[0];
#pragma unroll
        for (int w = 1; w < 8; ++w) m = fmaxf(m, redm[w]);

        v.x = expf(v.x - m); v.y = expf(v.y - m);
        v.z = expf(v.z - m); v.w = expf(v.w - m);
        float s = v.x + v.y + v.z + v.w;
#pragma unroll
        for (int off = 1; off < 64; off <<= 1)
            s += __shfl_xor(s, off);
        if (lane == 0) reds[wave] = s;
        __syncthreads();
        s = reds[0];
#pragma unroll
        for (int w = 1; w < 8; ++w) s += reds[w];

        const float inv = 1.0f / s;
        v *= inv;
        ((f4*)(out + (size_t)b * T_DIM))[tid] = v;
        __syncthreads();  // protect redm/reds before next row
    }
}

extern "C" void kernel_launch(void* const* d_in, const int* in_sizes, int n_in,
                              void* d_out, int out_size, void* d_ws, size_t ws_size,
                              hipStream_t stream) {
    const float* hidden = (const float*)d_in[0];  // [1,B,H]
    const float* enc    = (const float*)d_in[1];  // [T,B,H]
    const float* W      = (const float*)d_in[2];  // [H,H]
    // d_in[3] = b_attn: per-b constant under softmax -> cancels exactly.

    float* out      = (float*)d_out;                        // [B,1,T]
    float* q        = (float*)d_ws;                         // B*H  (256 KB)
    float* scores   = (float*)d_ws + (size_t)B_DIM * H_DIM; // B*T  (512 KB)
    int*   counters = (int*)(scores + (size_t)B_DIM * T_DIM); // 4 ints

    qproj_kernel<<<dim3(H_DIM / 256, B_DIM / 4), 512, 0, stream>>>(
        hidden, W, q, counters);
    scores_softmax_kernel<<<dim3(T_DIM / TC, B_DIM / 16), 512, 0, stream>>>(
        enc, q, scores, counters, out);
}

// Round 9
// 125.861 us; speedup vs baseline: 2.4447x; 2.4447x over previous
//
#include <hip/hip_runtime.h>
#include <math.h>

#define T_DIM 2048
#define B_DIM 64
#define H_DIM 1024
#define TC 16  // t-values per block in scores kernel

typedef float f4 __attribute__((ext_vector_type(4)));

// ---------------------------------------------------------------------------
// K1: q[b,h] = sum_g hidden[b,g] * W[g,h]
// grid (4, 16), block 512 = 8 waves. Block: 4 b-rows x 256 h-cols; one W load
// feeds 4 b-accumulators. LDS reduce across waves.
// b_attn is constant in t under softmax -> dropped exactly.
// ---------------------------------------------------------------------------
__global__ __launch_bounds__(512) void qproj_kernel(
    const float* __restrict__ hidden,
    const float* __restrict__ W,
    float* __restrict__ q) {
    const int b0   = blockIdx.y * 4;
    const int h0   = blockIdx.x * 256;
    const int wave = threadIdx.x >> 6;
    const int lane = threadIdx.x & 63;

    __shared__ float hs[4][H_DIM];
    __shared__ f4    part[8][4][64];

    for (int i = threadIdx.x; i < 4 * H_DIM; i += 512)
        hs[i >> 10][i & 1023] = hidden[(size_t)b0 * H_DIM + i];
    __syncthreads();

    const int gbase = wave * 128;
    const f4* Wv = (const f4*)(W + (size_t)gbase * H_DIM + h0);
    f4 acc0 = {0,0,0,0}, acc1 = {0,0,0,0}, acc2 = {0,0,0,0}, acc3 = {0,0,0,0};
#pragma unroll 4
    for (int g = 0; g < 128; ++g) {
        const f4 wv = Wv[g * 256 + lane];
        acc0 += hs[0][gbase + g] * wv;
        acc1 += hs[1][gbase + g] * wv;
        acc2 += hs[2][gbase + g] * wv;
        acc3 += hs[3][gbase + g] * wv;
    }
    part[wave][0][lane] = acc0;
    part[wave][1][lane] = acc1;
    part[wave][2][lane] = acc2;
    part[wave][3][lane] = acc3;
    __syncthreads();

    if (wave < 4) {  // wave w reduces b-row w
        f4 s = part[0][wave][lane];
#pragma unroll
        for (int w = 1; w < 8; ++w) s += part[w][wave][lane];
        ((f4*)(q + (size_t)(b0 + wave) * H_DIM + h0))[lane] = s;
    }
}

// ---------------------------------------------------------------------------
// K2 (dominant): scores[b][t] = sum_h enc[t,b,h] * q[b,h]
// 2 rows (b, b+1) per wave -> qf 32 VGPR, high occupancy (~6 waves/SIMD).
// Batched parity butterfly: 6 shuffles reduce BOTH rows at once.
// grid (T/TC, B/16) = (128, 4) = 512 blocks (2/CU), 512 thr (8 waves).
// Wave w owns b0 = y*16 + 2w (same b's for every t -> q stays in registers).
// A/B this round: plain (cached) enc loads instead of nontemporal.
// ---------------------------------------------------------------------------
__global__ __launch_bounds__(512) void scores_kernel(
    const float* __restrict__ enc,
    const float* __restrict__ q,
    float* __restrict__ scores) {
    const int wave = threadIdx.x >> 6;
    const int lane = threadIdx.x & 63;
    const int t0   = blockIdx.x * TC;
    const int b0   = blockIdx.y * 16 + wave * 2;

    f4 qf0[4], qf1[4];
    {
        const f4* qv0 = (const f4*)(q + (size_t)b0 * H_DIM);
        const f4* qv1 = (const f4*)(q + (size_t)(b0 + 1) * H_DIM);
#pragma unroll
        for (int k = 0; k < 4; ++k) {
            qf0[k] = qv0[k * 64 + lane];
            qf1[k] = qv1[k * 64 + lane];
        }
    }

#pragma unroll 2
    for (int tt = 0; tt < TC; ++tt) {
        const int t = t0 + tt;
        const f4* e0p = (const f4*)(enc + ((size_t)t * B_DIM + b0) * H_DIM);
        const f4* e1p = e0p + 256;  // row b0+1

        f4 E0[4], E1[4];
#pragma unroll
        for (int k = 0; k < 4; ++k) E0[k] = e0p[k * 64 + lane];
#pragma unroll
        for (int k = 0; k < 4; ++k) E1[k] = e1p[k * 64 + lane];

        float a0 = 0.f, a1 = 0.f;
#pragma unroll
        for (int k = 0; k < 4; ++k) {
            a0 += E0[k].x * qf0[k].x + E0[k].y * qf0[k].y +
                  E0[k].z * qf0[k].z + E0[k].w * qf0[k].w;
            a1 += E1[k].x * qf1[k].x + E1[k].y * qf1[k].y +
                  E1[k].z * qf1[k].z + E1[k].w * qf1[k].w;
        }

        // Parity butterfly: lane parity selects which row's sum it carries.
        const bool odd = lane & 1;
        float m = odd ? a1 : a0;
        float o = odd ? a0 : a1;
        m += __shfl_xor(o, 1);
#pragma unroll
        for (int off = 2; off < 64; off <<= 1)
            m += __shfl_xor(m, off);

        if (lane < 2)
            scores[(size_t)(b0 + lane) * T_DIM + t] = m;
    }
}

// ---------------------------------------------------------------------------
// K3: out[b,0,t] = softmax_t(scores[b][t]); block per b, 512 thr,
// one f4 per thread — fully coalesced.
// ---------------------------------------------------------------------------
__global__ __launch_bounds__(512) void softmax_kernel(
    const float* __restrict__ scores,
    float* __restrict__ out) {
    const int b    = blockIdx.x;
    const int tid  = threadIdx.x;
    const int wave = tid >> 6;
    const int lane = tid & 63;

    f4 v = ((const f4*)(scores + (size_t)b * T_DIM))[tid];

    float m = fmaxf(fmaxf(v.x, v.y), fmaxf(v.z, v.w));
#pragma unroll
    for (int off = 1; off < 64; off <<= 1)
        m = fmaxf(m, __shfl_xor(m, off));

    __shared__ float redm[8], reds[8];
    if (lane == 0) redm[wave] = m;
    __syncthreads();
    m = redm[0];
#pragma unroll
    for (int w = 1; w < 8; ++w) m = fmaxf(m, redm[w]);

    v.x = expf(v.x - m); v.y = expf(v.y - m);
    v.z = expf(v.z - m); v.w = expf(v.w - m);
    float s = v.x + v.y + v.z + v.w;
#pragma unroll
    for (int off = 1; off < 64; off <<= 1)
        s += __shfl_xor(s, off);
    if (lane == 0) reds[wave] = s;
    __syncthreads();
    s = reds[0];
#pragma unroll
    for (int w = 1; w < 8; ++w) s += reds[w];

    const float inv = 1.0f / s;
    v *= inv;
    ((f4*)(out + (size_t)b * T_DIM))[tid] = v;
}

extern "C" void kernel_launch(void* const* d_in, const int* in_sizes, int n_in,
                              void* d_out, int out_size, void* d_ws, size_t ws_size,
                              hipStream_t stream) {
    const float* hidden = (const float*)d_in[0];  // [1,B,H]
    const float* enc    = (const float*)d_in[1];  // [T,B,H]
    const float* W      = (const float*)d_in[2];  // [H,H]
    // d_in[3] = b_attn: per-b constant under softmax -> cancels exactly.

    float* out    = (float*)d_out;                        // [B,1,T]
    float* q      = (float*)d_ws;                         // B*H  (256 KB)
    float* scores = (float*)d_ws + (size_t)B_DIM * H_DIM; // B*T  (512 KB)

    qproj_kernel  <<<dim3(H_DIM / 256, B_DIM / 4), 512, 0, stream>>>(hidden, W, q);
    scores_kernel <<<dim3(T_DIM / TC, B_DIM / 16), 512, 0, stream>>>(enc, q, scores);
    softmax_kernel<<<dim3(B_DIM),                  512, 0, stream>>>(scores, out);
}

// Round 10
// 98.433 us; speedup vs baseline: 3.1259x; 1.2787x over previous
//
#include <hip/hip_runtime.h>
#include <math.h>

#define T_DIM 2048
#define B_DIM 64
#define H_DIM 1024
#define TC 16  // t-values per block in scores kernel

typedef float f4 __attribute__((ext_vector_type(4)));

// ---------------------------------------------------------------------------
// K1: q[b,h] = sum_g hidden[b,g] * W[g,h]
// grid (4, 16), block 512 = 8 waves. Block: 4 b-rows x 256 h-cols; one W load
// feeds 4 b-accumulators. LDS reduce across waves.
// b_attn is constant in t under softmax -> dropped exactly.
// ---------------------------------------------------------------------------
__global__ __launch_bounds__(512) void qproj_kernel(
    const float* __restrict__ hidden,
    const float* __restrict__ W,
    float* __restrict__ q) {
    const int b0   = blockIdx.y * 4;
    const int h0   = blockIdx.x * 256;
    const int wave = threadIdx.x >> 6;
    const int lane = threadIdx.x & 63;

    __shared__ float hs[4][H_DIM];
    __shared__ f4    part[8][4][64];

    for (int i = threadIdx.x; i < 4 * H_DIM; i += 512)
        hs[i >> 10][i & 1023] = hidden[(size_t)b0 * H_DIM + i];
    __syncthreads();

    const int gbase = wave * 128;
    const f4* Wv = (const f4*)(W + (size_t)gbase * H_DIM + h0);
    f4 acc0 = {0,0,0,0}, acc1 = {0,0,0,0}, acc2 = {0,0,0,0}, acc3 = {0,0,0,0};
#pragma unroll 4
    for (int g = 0; g < 128; ++g) {
        const f4 wv = Wv[g * 256 + lane];
        acc0 += hs[0][gbase + g] * wv;
        acc1 += hs[1][gbase + g] * wv;
        acc2 += hs[2][gbase + g] * wv;
        acc3 += hs[3][gbase + g] * wv;
    }
    part[wave][0][lane] = acc0;
    part[wave][1][lane] = acc1;
    part[wave][2][lane] = acc2;
    part[wave][3][lane] = acc3;
    __syncthreads();

    if (wave < 4) {  // wave w reduces b-row w
        f4 s = part[0][wave][lane];
#pragma unroll
        for (int w = 1; w < 8; ++w) s += part[w][wave][lane];
        ((f4*)(q + (size_t)(b0 + wave) * H_DIM + h0))[lane] = s;
    }
}

// ---------------------------------------------------------------------------
// K2 (dominant): scores[b][t] = sum_h enc[t,b,h] * q[b,h]
// 2 rows (b, b+1) per wave -> qf 32 VGPR, high occupancy (~6 waves/SIMD).
// Batched parity butterfly: 6 shuffles reduce BOTH rows at once.
// grid (T/TC, B/16) = (128, 4) = 512 blocks (2/CU), 512 thr (8 waves).
// Wave w owns b0 = y*16 + 2w (same b's for every t -> q stays in registers).
// NONTEMPORAL enc loads: measured +27 us (R9 A/B) — the 512 MB single-pass
// stream must not allocate in L2.
// ---------------------------------------------------------------------------
__global__ __launch_bounds__(512) void scores_kernel(
    const float* __restrict__ enc,
    const float* __restrict__ q,
    float* __restrict__ scores) {
    const int wave = threadIdx.x >> 6;
    const int lane = threadIdx.x & 63;
    const int t0   = blockIdx.x * TC;
    const int b0   = blockIdx.y * 16 + wave * 2;

    f4 qf0[4], qf1[4];
    {
        const f4* qv0 = (const f4*)(q + (size_t)b0 * H_DIM);
        const f4* qv1 = (const f4*)(q + (size_t)(b0 + 1) * H_DIM);
#pragma unroll
        for (int k = 0; k < 4; ++k) {
            qf0[k] = qv0[k * 64 + lane];
            qf1[k] = qv1[k * 64 + lane];
        }
    }

#pragma unroll 2
    for (int tt = 0; tt < TC; ++tt) {
        const int t = t0 + tt;
        const f4* e0p = (const f4*)(enc + ((size_t)t * B_DIM + b0) * H_DIM);
        const f4* e1p = e0p + 256;  // row b0+1

        f4 E0[4], E1[4];
#pragma unroll
        for (int k = 0; k < 4; ++k)
            E0[k] = __builtin_nontemporal_load(&e0p[k * 64 + lane]);
#pragma unroll
        for (int k = 0; k < 4; ++k)
            E1[k] = __builtin_nontemporal_load(&e1p[k * 64 + lane]);

        float a0 = 0.f, a1 = 0.f;
#pragma unroll
        for (int k = 0; k < 4; ++k) {
            a0 += E0[k].x * qf0[k].x + E0[k].y * qf0[k].y +
                  E0[k].z * qf0[k].z + E0[k].w * qf0[k].w;
            a1 += E1[k].x * qf1[k].x + E1[k].y * qf1[k].y +
                  E1[k].z * qf1[k].z + E1[k].w * qf1[k].w;
        }

        // Parity butterfly: lane parity selects which row's sum it carries.
        const bool odd = lane & 1;
        float m = odd ? a1 : a0;
        float o = odd ? a0 : a1;
        m += __shfl_xor(o, 1);
#pragma unroll
        for (int off = 2; off < 64; off <<= 1)
            m += __shfl_xor(m, off);

        if (lane < 2)
            scores[(size_t)(b0 + lane) * T_DIM + t] = m;
    }
}

// ---------------------------------------------------------------------------
// K3: out[b,0,t] = softmax_t(scores[b][t]); block per b, 512 thr,
// one f4 per thread — fully coalesced.
// ---------------------------------------------------------------------------
__global__ __launch_bounds__(512) void softmax_kernel(
    const float* __restrict__ scores,
    float* __restrict__ out) {
    const int b    = blockIdx.x;
    const int tid  = threadIdx.x;
    const int wave = tid >> 6;
    const int lane = tid & 63;

    f4 v = ((const f4*)(scores + (size_t)b * T_DIM))[tid];

    float m = fmaxf(fmaxf(v.x, v.y), fmaxf(v.z, v.w));
#pragma unroll
    for (int off = 1; off < 64; off <<= 1)
        m = fmaxf(m, __shfl_xor(m, off));

    __shared__ float redm[8], reds[8];
    if (lane == 0) redm[wave] = m;
    __syncthreads();
    m = redm[0];
#pragma unroll
    for (int w = 1; w < 8; ++w) m = fmaxf(m, redm[w]);

    v.x = expf(v.x - m); v.y = expf(v.y - m);
    v.z = expf(v.z - m); v.w = expf(v.w - m);
    float s = v.x + v.y + v.z + v.w;
#pragma unroll
    for (int off = 1; off < 64; off <<= 1)
        s += __shfl_xor(s, off);
    if (lane == 0) reds[wave] = s;
    __syncthreads();
    s = reds[0];
#pragma unroll
    for (int w = 1; w < 8; ++w) s += reds[w];

    const float inv = 1.0f / s;
    v *= inv;
    ((f4*)(out + (size_t)b * T_DIM))[tid] = v;
}

extern "C" void kernel_launch(void* const* d_in, const int* in_sizes, int n_in,
                              void* d_out, int out_size, void* d_ws, size_t ws_size,
                              hipStream_t stream) {
    const float* hidden = (const float*)d_in[0];  // [1,B,H]
    const float* enc    = (const float*)d_in[1];  // [T,B,H]
    const float* W      = (const float*)d_in[2];  // [H,H]
    // d_in[3] = b_attn: per-b constant under softmax -> cancels exactly.

    float* out    = (float*)d_out;                        // [B,1,T]
    float* q      = (float*)d_ws;                         // B*H  (256 KB)
    float* scores = (float*)d_ws + (size_t)B_DIM * H_DIM; // B*T  (512 KB)

    qproj_kernel  <<<dim3(H_DIM / 256, B_DIM / 4), 512, 0, stream>>>(hidden, W, q);
    scores_kernel <<<dim3(T_DIM / TC, B_DIM / 16), 512, 0, stream>>>(enc, q, scores);
    softmax_kernel<<<dim3(B_DIM),                  512, 0, stream>>>(scores, out);
}